// Round 11
// baseline (441.536 us; speedup 1.0000x reference)
//
#include <hip/hip_runtime.h>
#include <hip/hip_bf16.h>

#define S_LEN 2048
#define D_DIM 64
#define QT    32
#define KT    64
#define NTHR  256
#define NKT   (S_LEN / KT)          // 32
#define NQT   (S_LEN / QT)          // 64
#define NBLK  (NQT * 32)            // 2048 blocks = 8/CU
#define PROB_ELEMS 4194304LL        // 2*16*2048*64

typedef float        f32x4  __attribute__((ext_vector_type(4)));
typedef int          i32x4  __attribute__((ext_vector_type(4)));
typedef unsigned int u32x4  __attribute__((ext_vector_type(4)));
typedef short        bf16x8 __attribute__((ext_vector_type(8)));

__device__ __forceinline__ unsigned short f2bf(float f) {
    return __builtin_bit_cast(unsigned short, __float2bfloat16(f));
}
__device__ __forceinline__ int swzc(int row, int ch) {
    return ch ^ ((row ^ (row >> 3)) & 7);
}
__device__ __forceinline__ float4 scale4(float4 v, float s) {
    v.x *= s; v.y *= s; v.z *= s; v.w *= s; return v;
}
__device__ __forceinline__ u32x4 packbf(float4 a, float4 b) {
    u32x4 r;
    r[0] = (unsigned)f2bf(a.x) | ((unsigned)f2bf(a.y) << 16);
    r[1] = (unsigned)f2bf(a.z) | ((unsigned)f2bf(a.w) << 16);
    r[2] = (unsigned)f2bf(b.x) | ((unsigned)f2bf(b.y) << 16);
    r[3] = (unsigned)f2bf(b.z) | ((unsigned)f2bf(b.w) << 16);
    return r;
}
__device__ __forceinline__ unsigned cvtpk(float lo, float hi) {
    unsigned r;
    asm("v_cvt_pk_bf16_f32 %0, %1, %2" : "=v"(r) : "v"(lo), "v"(hi));
    return r;
}
#define BC8(x) __builtin_bit_cast(bf16x8, (x))
#define MFMA(A, B, C) __builtin_amdgcn_mfma_f32_16x16x32_bf16((A), (B), (C), 0, 0, 0)

// -------------------------------------------------------------------------
__global__ void mask_probe_kernel(const unsigned int* __restrict__ m,
                                  int* __restrict__ flag) {
    unsigned int v = m[threadIdx.x];
    unsigned long long ok = __ballot(v <= 1u);
    if (threadIdx.x == 0) *flag = (ok == ~0ULL) ? 1 : 0;
}

// -------------------------------------------------------------------------
// Prep for the k-split geometry. Per (bh,kt) tile (8 KB each tensor):
//  K frag fi = wk*4 + n*2 + f : lane l=(c,g) -> K[kt*64+wk*32+n*16+c][f*32+8g+j]
//  V frag fi = wk*4 + df      : lane l=(c,g) -> V[kt*64+wk*32+8g+j][df*16+c]
// -------------------------------------------------------------------------
#define KFRAG_T 524288   // 32bh*32kt*2wk*2n*2f*64lane
#define VFRAG_T 524288   // 32bh*32kt*2wk*4df*64lane
__global__ __launch_bounds__(256)
void kv_prep_split(const float* __restrict__ Kg, const float* __restrict__ Vg,
                   unsigned* __restrict__ Kf, unsigned* __restrict__ Vf) {
    int tid = blockIdx.x * 256 + threadIdx.x;
    if (tid < KFRAG_T) {
        int l = tid & 63, f = (tid >> 6) & 1, n = (tid >> 7) & 1;
        int wk = (tid >> 8) & 1, kt = (tid >> 9) & 31, bh = tid >> 14;
        int c = l & 15, g = l >> 4;
        const float* src = Kg
            + (long long)(bh * S_LEN + kt * KT + wk * 32 + n * 16 + c) * D_DIM
            + f * 32 + g * 8;
        float4 a = *(const float4*)src, b = *(const float4*)(src + 4);
        unsigned* dst = Kf + ((unsigned)(bh * NKT + kt) << 11)
                           + (unsigned)((wk * 4 + n * 2 + f) * 64 + l) * 4u;
        *(u32x4*)dst = packbf(a, b);
    } else if (tid < KFRAG_T + VFRAG_T) {
        int idx = tid - KFRAG_T;
        int l = idx & 63, df = (idx >> 6) & 3;
        int wk = (idx >> 8) & 1, kt = (idx >> 9) & 31, bh = idx >> 14;
        int c = l & 15, g = l >> 4;
        const float* vb = Vg
            + (long long)(bh * S_LEN + kt * KT + wk * 32 + g * 8) * D_DIM
            + df * 16 + c;
        u32x4 o;
        #pragma unroll
        for (int s = 0; s < 4; ++s) {
            float lo = vb[(2 * s) * D_DIM];
            float hi = vb[(2 * s + 1) * D_DIM];
            o[s] = (unsigned)f2bf(lo) | ((unsigned)f2bf(hi) << 16);
        }
        unsigned* dst = Vf + ((unsigned)(bh * NKT + kt) << 11)
                           + (unsigned)((wk * 4 + df) * 64 + l) * 4u;
        *(u32x4*)dst = o;
    }
}

// ---- main-kernel macros (capture scope vars) ----
#define LOAD_KF(DST, KTV)                                                   \
    { const u32x4* p_ = (const u32x4*)(Kf + tbase + (unsigned)(KTV) * 2048u \
                                       + (unsigned)wk * 1024u) + lane;      \
      DST[0] = p_[0]; DST[1] = p_[64]; DST[2] = p_[128]; DST[3] = p_[192]; }

#define LOAD_VF(DST, KTV)                                                   \
    { const u32x4* p_ = (const u32x4*)(Vf + tbase + (unsigned)(KTV) * 2048u \
                                       + (unsigned)wk * 1024u) + lane;      \
      DST[0] = p_[0]; DST[1] = p_[64]; DST[2] = p_[128]; DST[3] = p_[192]; }

#define PREF_MSK(M4, R2, KTV)                                               \
    { if (mask32) {                                                         \
        _Pragma("unroll")                                                   \
        for (int n_ = 0; n_ < 2; ++n_)                                      \
          M4[n_] = *(const i32x4*)(maskI + rowoff                           \
                     + (unsigned)((KTV) * KT + wk * 32 + n_ * 16 + 4 * g)); \
      } else {                                                              \
        _Pragma("unroll")                                                   \
        for (int n_ = 0; n_ < 2; ++n_)                                      \
          R2[n_] = *(const unsigned*)(maskB + rowoff                        \
                     + (unsigned)((KTV) * KT + wk * 32 + n_ * 16 + 4 * g)); \
      } }

#define BITS8(DST, M4, R2)                                                  \
    { unsigned bz_ = 0u;                                                    \
      if (mask32) {                                                         \
        _Pragma("unroll")                                                   \
        for (int n_ = 0; n_ < 2; ++n_)                                      \
          bz_ |= ((M4[n_][0] ? 1u : 0u) | (M4[n_][1] ? 2u : 0u) |           \
                  (M4[n_][2] ? 4u : 0u) | (M4[n_][3] ? 8u : 0u)) << (n_*4); \
      } else {                                                              \
        _Pragma("unroll")                                                   \
        for (int n_ = 0; n_ < 2; ++n_) { unsigned mb_ = R2[n_];             \
          bz_ |= (((mb_ & 0xffu) ? 1u : 0u) | ((mb_ & 0xff00u) ? 2u : 0u) | \
                  ((mb_ & 0xff0000u) ? 4u : 0u) |                           \
                  ((mb_ & 0xff000000u) ? 8u : 0u)) << (n_ * 4); }           \
      }                                                                     \
      (DST) = bz_; }

#define LOAD_B8(DST, KTV)                                                   \
    { if (useWS) (DST) = (unsigned)bitsWS[bitbase + (unsigned)(KTV)*NTHR];  \
      else { i32x4 mq_[2]; unsigned rq_[2];                                 \
             PREF_MSK(mq_, rq_, KTV) BITS8(DST, mq_, rq_) } }

#define QK4(KC, A0, A1)                                                     \
    { A0 = (f32x4){0.f,0.f,0.f,0.f}; A1 = (f32x4){0.f,0.f,0.f,0.f};         \
      A0 = MFMA(BC8(KC[0]), qf0, A0); A0 = MFMA(BC8(KC[1]), qf1, A0);       \
      A1 = MFMA(BC8(KC[2]), qf0, A1); A1 = MFMA(BC8(KC[3]), qf1, A1); }

#define PH1(KC, BITS)                                                       \
    { f32x4 a0_, a1_; QK4(KC, a0_, a1_)                                     \
      unsigned bb_ = (BITS);                                                \
      psum += (bb_ &   1u) ? 0.f : __expf(a0_[0]);                          \
      psum += (bb_ &   2u) ? 0.f : __expf(a0_[1]);                          \
      psum += (bb_ &   4u) ? 0.f : __expf(a0_[2]);                          \
      psum += (bb_ &   8u) ? 0.f : __expf(a0_[3]);                          \
      psum += (bb_ &  16u) ? 0.f : __expf(a1_[0]);                          \
      psum += (bb_ &  32u) ? 0.f : __expf(a1_[1]);                          \
      psum += (bb_ &  64u) ? 0.f : __expf(a1_[2]);                          \
      psum += (bb_ & 128u) ? 0.f : __expf(a1_[3]); }

#define PH2(KC, VC, BITS, KTV)                                              \
    { f32x4 a0_, a1_; QK4(KC, a0_, a1_)                                     \
      unsigned bb_ = (BITS);                                                \
      f32x4 e0_, e1_;                                                       \
      e0_[0] = (bb_ &   1u) ? 0.f : __expf(a0_[0]) * rinv;                  \
      e0_[1] = (bb_ &   2u) ? 0.f : __expf(a0_[1]) * rinv;                  \
      e0_[2] = (bb_ &   4u) ? 0.f : __expf(a0_[2]) * rinv;                  \
      e0_[3] = (bb_ &   8u) ? 0.f : __expf(a0_[3]) * rinv;                  \
      e1_[0] = (bb_ &  16u) ? 0.f : __expf(a1_[0]) * rinv;                  \
      e1_[1] = (bb_ &  32u) ? 0.f : __expf(a1_[1]) * rinv;                  \
      e1_[2] = (bb_ &  64u) ? 0.f : __expf(a1_[2]) * rinv;                  \
      e1_[3] = (bb_ & 128u) ? 0.f : __expf(a1_[3]) * rinv;                  \
      unsigned ix_ = rowoff + (unsigned)((KTV) * KT + wk * 32 + 4 * g);     \
      *(f32x4*)(attnOut + ix_)      = e0_;                                  \
      *(f32x4*)(attnOut + ix_ + 16) = e1_;                                  \
      { uint2 p0_, p1_;                                                     \
        p0_.x = cvtpk(e0_[0], e0_[1]); p0_.y = cvtpk(e0_[2], e0_[3]);       \
        p1_.x = cvtpk(e1_[0], e1_[1]); p1_.y = cvtpk(e1_[2], e1_[3]);       \
        *(uint2*)(PsW + c * 80 + 8 * g)      = p0_;                         \
        *(uint2*)(PsW + c * 80 + 32 + 8 * g) = p1_; }                       \
      { bf16x8 pa_ = *(const bf16x8*)(PsW + c * 80 + 16 * g);               \
        __builtin_amdgcn_s_setprio(1);                                      \
        pacc[0] = MFMA(pa_, BC8(VC[0]), pacc[0]);                           \
        pacc[1] = MFMA(pa_, BC8(VC[1]), pacc[1]);                           \
        pacc[2] = MFMA(pa_, BC8(VC[2]), pacc[2]);                           \
        pacc[3] = MFMA(pa_, BC8(VC[3]), pacc[3]);                           \
        __builtin_amdgcn_s_setprio(0); } }

// -------------------------------------------------------------------------
// Main kernel: 2048 blocks (q32 each), 4 waves = 2 q-halves x 2 k-slices.
// Barrier-free k-loop; wave-private P; cross-wave rowsum + pacc reduces.
// -------------------------------------------------------------------------
#define QS_OFF 0        // 4 KB Q staging (also reused by pacc exchange)
#define PS_OFF 4096     // 4 x 1280 B wave-private P
#define RS_OFF 9216     // 256 B rowsum exchange
#define SMB    9472

__global__ __launch_bounds__(NTHR, 4)
void attn_fused_split(const float* __restrict__ Qg,
                      const unsigned* __restrict__ Kf,
                      const unsigned* __restrict__ Vf,
                      const unsigned char* __restrict__ maskB,
                      const int* __restrict__ flagp,
                      unsigned char* __restrict__ bitsWS, int useWS,
                      float* __restrict__ attnOut, float* __restrict__ probOut) {
    __shared__ unsigned char sm[SMB];

    const int t = threadIdx.x;
    const int lane = t & 63, w = t >> 6, c = lane & 15, g = lane >> 4;
    const int wq = w >> 1, wk = w & 1;

    const int orig = blockIdx.x;
    const int virt = (orig & 7) * 256 + (orig >> 3);   // XCD swizzle: 4 bh/XCD
    const int qt = virt & (NQT - 1), bh = virt >> 6;
    const int mask32 = *flagp;
    const int* maskI = (const int*)maskB;

    const int qrowbase = bh * S_LEN + qt * QT;
    const unsigned rowoff = (unsigned)(qrowbase + wq * 16 + c) * (unsigned)S_LEN;
    const unsigned bitbase = (unsigned)virt * NKT * NTHR + (unsigned)t;
    const unsigned tbase = (unsigned)(bh * NKT) << 11;   // u32 idx, tile 0
    unsigned char* PsW = sm + PS_OFF + w * 1280;

    // ---- stage Q (pre-scaled 1/8) -> Qs; load this wave's B(Q) frags ----
    {
        int row = t >> 3, ch = t & 7;
        const float* src = Qg + (qrowbase + row) * D_DIM + ch * 8;
        float4 a = *(const float4*)src, b = *(const float4*)(src + 4);
        *(u32x4*)(sm + QS_OFF + row * 128 + swzc(row, ch) * 16) =
            packbf(scale4(a, 0.125f), scale4(b, 0.125f));
    }
    __syncthreads();
    bf16x8 qf0, qf1;
    {
        int row = wq * 16 + c;
        qf0 = *(const bf16x8*)(sm + QS_OFF + row * 128 + swzc(row, g) * 16);
        qf1 = *(const bf16x8*)(sm + QS_OFF + row * 128 + swzc(row, 4 + g) * 16);
    }

    // =================== PHASE 1: rowsum + mask bits ===================
    float psum = 0.f;
    {
        u32x4 kA[4], kB[4];
        i32x4 mA[2], mB[2];
        unsigned rA[2], rB[2], bA, bB;
        LOAD_KF(kA, 0)
        PREF_MSK(mA, rA, 0)
        for (int j = 0; j < NKT / 2; ++j) {
            const int ktA = 2 * j, ktB = 2 * j + 1;
            LOAD_KF(kB, ktB)
            PREF_MSK(mB, rB, ktB)
            BITS8(bA, mA, rA)
            PH1(kA, bA)
            if (useWS) bitsWS[bitbase + (unsigned)ktA * NTHR] = (unsigned char)bA;
            if (j + 1 < NKT / 2) {
                LOAD_KF(kA, ktA + 2)
                PREF_MSK(mA, rA, ktA + 2)
            }
            BITS8(bB, mB, rB)
            PH1(kB, bB)
            if (useWS) bitsWS[bitbase + (unsigned)ktB * NTHR] = (unsigned char)bB;
        }
    }
    // cross-g then cross-wave (k-slice pair) rowsum
    {
        float s = psum;
        s += __shfl_xor(s, 16, 64);
        s += __shfl_xor(s, 32, 64);
        float* Rs = (float*)(sm + RS_OFF);
        if (lane < 16) Rs[w * 16 + c] = s;
    }
    __syncthreads();
    const float rinv = 1.0f /
        (((const float*)(sm + RS_OFF))[(wq * 2 + 0) * 16 + c] +
         ((const float*)(sm + RS_OFF))[(wq * 2 + 1) * 16 + c]);

    // =================== PHASE 2: attn + PV (barrier-free) ===================
    f32x4 pacc[4];
    #pragma unroll
    for (int d = 0; d < 4; ++d) pacc[d] = (f32x4){0.f, 0.f, 0.f, 0.f};
    {
        u32x4 kA[4], kB[4], vA[4], vB[4];
        unsigned bA, bB;
        LOAD_KF(kA, 0)
        LOAD_B8(bA, 0)
        for (int j = 0; j < NKT / 2; ++j) {
            const int ktA = 2 * j, ktB = 2 * j + 1;
            LOAD_KF(kB, ktB)
            LOAD_B8(bB, ktB)
            LOAD_VF(vA, ktA)
            PH2(kA, vA, bA, ktA)
            if (j + 1 < NKT / 2) {
                LOAD_KF(kA, ktA + 2)
                LOAD_B8(bA, ktA + 2)
            }
            LOAD_VF(vB, ktB)
            PH2(kB, vB, bB, ktB)
        }
    }

    // ---- cross-wave pacc reduce (k-slice pairs) + prob store ----
    __syncthreads();               // all Ps use complete before reuse of sm
    if (wk == 1) {
        #pragma unroll
        for (int df = 0; df < 4; ++df)
            *(f32x4*)(sm + wq * 4096 + lane * 64 + df * 16) = pacc[df];
    }
    __syncthreads();
    if (wk == 0) {
        #pragma unroll
        for (int df = 0; df < 4; ++df) {
            f32x4 o = pacc[df] +
                *(const f32x4*)(sm + wq * 4096 + lane * 64 + df * 16);
            #pragma unroll
            for (int r = 0; r < 4; ++r) {
                int qe = qrowbase + wq * 16 + 4 * g + r;
                probOut[(long long)qe * D_DIM + df * 16 + c] = o[r];
            }
        }
    }
}

// -------------------------------------------------------------------------
// Fallback (R10 register-staging kernel, 1024 blocks) if ws too small.
// -------------------------------------------------------------------------
#define FKT 64
#define LOAD_MBITS(DST, KTV)                                                \
    { unsigned bz_ = 0u;                                                    \
      _Pragma("unroll")                                                     \
      for (int n_ = 0; n_ < 4; ++n_) {                                      \
        unsigned idx_ = rowoff + (unsigned)((KTV) * FKT + n_ * 16 + 4 * g); \
        if (mask32) {                                                       \
            i32x4 m4_ = *(const i32x4*)(maskI + idx_);                      \
            bz_ |= ((m4_[0] ? 1u : 0u) | (m4_[1] ? 2u : 0u) |               \
                    (m4_[2] ? 4u : 0u) | (m4_[3] ? 8u : 0u)) << (n_ * 4);   \
        } else {                                                            \
            unsigned mb_ = *(const unsigned*)(maskB + idx_);                \
            bz_ |= (((mb_ & 0xffu) ? 1u : 0u) | ((mb_ & 0xff00u) ? 2u : 0u) | \
                    ((mb_ & 0xff0000u) ? 4u : 0u) |                         \
                    ((mb_ & 0xff000000u) ? 8u : 0u)) << (n_ * 4);           \
        } }                                                                 \
      (DST) = bz_; }

#define LOAD_BITS2(DST, KTV)                                                \
    { if (useWS) (DST) = (unsigned)bitsW16[bitbase + (unsigned)(KTV)*NTHR]; \
      else LOAD_MBITS(DST, KTV) }

#define PH1_TILE(KS, BITS)                                                  \
    { unsigned bb = (BITS);                                                 \
      _Pragma("unroll")                                                     \
      for (int n = 0; n < 4; ++n) {                                         \
        int rowk = n * 16 + c;                                              \
        bf16x8 kf0 = *(const bf16x8*)((KS) + rowk * 128 + swzc(rowk, g) * 16);     \
        bf16x8 kf1 = *(const bf16x8*)((KS) + rowk * 128 + swzc(rowk, 4 + g) * 16); \
        f32x4 acc = {0.f, 0.f, 0.f, 0.f};                                   \
        acc = MFMA(kf0, qf0, acc); acc = MFMA(kf1, qf1, acc);               \
        unsigned mb = bb >> (n * 4);                                        \
        psum += (mb & 1u) ? 0.f : __expf(acc[0]);                           \
        psum += (mb & 2u) ? 0.f : __expf(acc[1]);                           \
        psum += (mb & 4u) ? 0.f : __expf(acc[2]);                           \
        psum += (mb & 8u) ? 0.f : __expf(acc[3]);                           \
      } }

#define PH2_TILE(KS, VT, BITS, KTV)                                         \
    { unsigned bb = (BITS);                                                 \
      _Pragma("unroll")                                                     \
      for (int n = 0; n < 4; ++n) {                                         \
        int rowk = n * 16 + c;                                              \
        bf16x8 kf0 = *(const bf16x8*)((KS) + rowk * 128 + swzc(rowk, g) * 16);     \
        bf16x8 kf1 = *(const bf16x8*)((KS) + rowk * 128 + swzc(rowk, 4 + g) * 16); \
        f32x4 acc = {0.f, 0.f, 0.f, 0.f};                                   \
        acc = MFMA(kf0, qf0, acc); acc = MFMA(kf1, qf1, acc);               \
        unsigned mb = bb >> (n * 4);                                        \
        f32x4 ev;                                                           \
        ev[0] = (mb & 1u) ? 0.f : __expf(acc[0]) * rinv;                    \
        ev[1] = (mb & 2u) ? 0.f : __expf(acc[1]) * rinv;                    \
        ev[2] = (mb & 4u) ? 0.f : __expf(acc[2]) * rinv;                    \
        ev[3] = (mb & 8u) ? 0.f : __expf(acc[3]) * rinv;                    \
        unsigned idx0 = rowoff + (unsigned)((KTV) * FKT + n * 16 + 4 * g);  \
        *(f32x4*)(attnOut + idx0) = ev;                                     \
        uint2 pkv; pkv.x = cvtpk(ev[0], ev[1]); pkv.y = cvtpk(ev[2], ev[3]);\
        int kloc = n * 16 + 4 * g;                                          \
        *(uint2*)(Ps + ql * 128 + swzc(ql, kloc >> 3) * 16 + (kloc & 7) * 2) = pkv; \
      }                                                                     \
      { bf16x8 pa0 = *(const bf16x8*)(Ps + ql * 128 + swzc(ql, g) * 16);    \
        bf16x8 pa1 = *(const bf16x8*)(Ps + ql * 128 + swzc(ql, 4 + g) * 16);\
        _Pragma("unroll")                                                   \
        for (int df = 0; df < 4; ++df) {                                    \
            int d = df * 16 + c;                                            \
            bf16x8 vb0 = *(const bf16x8*)((VT) + d * 128 + swzc(d, g) * 16);     \
            bf16x8 vb1 = *(const bf16x8*)((VT) + d * 128 + swzc(d, 4 + g) * 16); \
            pacc[df] = MFMA(pa0, vb0, pacc[df]);                            \
            pacc[df] = MFMA(pa1, vb1, pacc[df]);                            \
        } } }

#define LOAD_K(KP, KTV)                                                     \
    { _Pragma("unroll")                                                     \
      for (int i = 0; i < 2; ++i) {                                         \
        int flat = i * NTHR + t, row = flat >> 3, ch = flat & 7;            \
        const float* src = Kg + (kbase + (KTV) * FKT + row) * D_DIM + ch*8; \
        float4 a = *(const float4*)src, b = *(const float4*)(src + 4);      \
        KP[i] = packbf(a, b);                                               \
      } }
#define STAGE_K(KS, KP)                                                     \
    { _Pragma("unroll")                                                     \
      for (int i = 0; i < 2; ++i) {                                         \
        int flat = i * NTHR + t, row = flat >> 3, ch = flat & 7;            \
        *(u32x4*)((KS) + row * 128 + swzc(row, ch) * 16) = KP[i];           \
      } }
#define LOAD_V(VP, KTV)                                                     \
    { const float* src = Vg + (kbase + (KTV) * FKT + k0v) * D_DIM + dgv*8;  \
      float4 a = *(const float4*)src, b = *(const float4*)(src + 4);        \
      float4 e4 = *(const float4*)(src + D_DIM);                            \
      float4 f4 = *(const float4*)(src + D_DIM + 4);                        \
      VP[0] = (unsigned)f2bf(a.x) | ((unsigned)f2bf(e4.x) << 16);           \
      VP[1] = (unsigned)f2bf(a.y) | ((unsigned)f2bf(e4.y) << 16);           \
      VP[2] = (unsigned)f2bf(a.z) | ((unsigned)f2bf(e4.z) << 16);           \
      VP[3] = (unsigned)f2bf(a.w) | ((unsigned)f2bf(e4.w) << 16);           \
      VP[4] = (unsigned)f2bf(b.x) | ((unsigned)f2bf(f4.x) << 16);           \
      VP[5] = (unsigned)f2bf(b.y) | ((unsigned)f2bf(f4.y) << 16);           \
      VP[6] = (unsigned)f2bf(b.z) | ((unsigned)f2bf(f4.z) << 16);           \
      VP[7] = (unsigned)f2bf(b.w) | ((unsigned)f2bf(f4.w) << 16); }
#define STAGE_V(VT, VP)                                                     \
    { _Pragma("unroll")                                                     \
      for (int jj = 0; jj < 8; ++jj) {                                      \
        int d = dgv * 8 + jj;                                               \
        *(unsigned*)((VT) + d * 128 + swzc(d, k0v >> 3) * 16 + (k0v & 7) * 2) = VP[jj]; \
      } }

__global__ __launch_bounds__(NTHR, 4)
void attn_fused_reg(const float* __restrict__ Qg, const float* __restrict__ Kg,
                    const float* __restrict__ Vg,
                    const unsigned char* __restrict__ maskB,
                    const int* __restrict__ flagp,
                    unsigned short* __restrict__ bitsW16, int useWS,
                    float* __restrict__ attnOut, float* __restrict__ probOut) {
    __shared__ unsigned char sm[40960];
    unsigned char* Ks0 = sm;
    unsigned char* Ks1 = sm + 8192;
    unsigned char* Vt0 = sm + 16384;
    unsigned char* Vt1 = sm + 24576;
    unsigned char* Ps  = sm + 32768;

    const int t = threadIdx.x;
    const int lane = t & 63, w = t >> 6, c = lane & 15, g = lane >> 4;
    (void)lane;

    const int orig = blockIdx.x;
    const int virt = (orig & 7) * 128 + (orig >> 3);
    const int qt = virt & 31, bh = virt >> 5;
    const int mask32 = *flagp;
    const int* maskI = (const int*)maskB;

    const int qrowbase = bh * S_LEN + qt * 64;
    const int kbase = bh * S_LEN;
    const int ql = w * 16 + c;
    const unsigned rowoff = (unsigned)(qrowbase + ql) * (unsigned)S_LEN;
    const unsigned bitbase = (unsigned)virt * NKT * NTHR + (unsigned)t;
    const int dgv = t & 7, k0v = (t >> 3) * 2;

    #pragma unroll
    for (int i = 0; i < 2; ++i) {
        int flat = i * NTHR + t, row = flat >> 3, ch = flat & 7;
        const float* src = Qg + (qrowbase + row) * D_DIM + ch * 8;
        float4 a = *(const float4*)src, b = *(const float4*)(src + 4);
        *(u32x4*)(Ps + row * 128 + swzc(row, ch) * 16) =
            packbf(scale4(a, 0.125f), scale4(b, 0.125f));
    }
    __syncthreads();
    bf16x8 qf0 = *(const bf16x8*)(Ps + ql * 128 + swzc(ql, g) * 16);
    bf16x8 qf1 = *(const bf16x8*)(Ps + ql * 128 + swzc(ql, 4 + g) * 16);
    __syncthreads();

    float psum = 0.f;
    u32x4 kpA[2], kpB[2];
    unsigned bA, bB;
    LOAD_K(kpA, 0)
    LOAD_MBITS(bA, 0)

    for (int j = 0; j < NKT / 2; ++j) {
        const int ktA = 2 * j, ktB = 2 * j + 1;
        STAGE_K(Ks0, kpA)
        LOAD_K(kpB, ktB)
        LOAD_MBITS(bB, ktB)
        __syncthreads();
        PH1_TILE(Ks0, bA)
        if (useWS) bitsW16[bitbase + (unsigned)ktA * NTHR] = (unsigned short)bA;
        STAGE_K(Ks1, kpB)
        if (j + 1 < NKT / 2) {
            LOAD_K(kpA, ktA + 2)
            LOAD_MBITS(bA, ktA + 2)
        }
        __syncthreads();
        PH1_TILE(Ks1, bB)
        if (useWS) bitsW16[bitbase + (unsigned)ktB * NTHR] = (unsigned short)bB;
    }

    float s = psum;
    s += __shfl_xor(s, 16, 64);
    s += __shfl_xor(s, 32, 64);
    const float rinv = 1.0f / s;

    f32x4 pacc[4];
    #pragma unroll
    for (int d = 0; d < 4; ++d) pacc[d] = (f32x4){0.f, 0.f, 0.f, 0.f};

    unsigned vpA[8], vpB[8];
    LOAD_K(kpA, 0)
    LOAD_V(vpA, 0)
    LOAD_BITS2(bA, 0)
    __syncthreads();

    for (int j = 0; j < NKT / 2; ++j) {
        const int ktA = 2 * j, ktB = 2 * j + 1;
        STAGE_K(Ks0, kpA)
        STAGE_V(Vt0, vpA)
        LOAD_K(kpB, ktB)
        LOAD_V(vpB, ktB)
        LOAD_BITS2(bB, ktB)
        __syncthreads();
        PH2_TILE(Ks0, Vt0, bA, ktA)
        STAGE_K(Ks1, kpB)
        STAGE_V(Vt1, vpB)
        if (j + 1 < NKT / 2) {
            LOAD_K(kpA, ktA + 2)
            LOAD_V(vpA, ktA + 2)
            LOAD_BITS2(bA, ktA + 2)
        }
        __syncthreads();
        PH2_TILE(Ks1, Vt1, bB, ktB)
    }

    #pragma unroll
    for (int df = 0; df < 4; ++df)
        #pragma unroll
        for (int r = 0; r < 4; ++r) {
            int qe = w * 16 + g * 4 + r;
            probOut[(long long)(qrowbase + qe) * D_DIM + df * 16 + c] = pacc[df][r];
        }
}

// -------------------------------------------------------------------------
extern "C" void kernel_launch(void* const* d_in, const int* in_sizes, int n_in,
                              void* d_out, int out_size, void* d_ws, size_t ws_size,
                              hipStream_t stream) {
    const float* Q = (const float*)d_in[0];
    const float* K = (const float*)d_in[1];
    const float* V = (const float*)d_in[2];
    const unsigned char* mask = (const unsigned char*)d_in[3];

    float* prob = (float*)d_out;
    float* attn = (float*)d_out + PROB_ELEMS;

    const size_t bits_bytes = 16777216ull;   // u8 x 2048x32x256 (== u16 fallback)
    const size_t kbf_bytes  = 8388608ull;    // per tensor
    int* flag = (int*)d_ws;
    unsigned char*  bits8  = (unsigned char*)((char*)d_ws + 256);
    unsigned short* bits16 = (unsigned short*)((char*)d_ws + 256);
    unsigned* Kf = (unsigned*)((char*)d_ws + 256 + bits_bytes);
    unsigned* Vf = (unsigned*)((char*)d_ws + 256 + bits_bytes + kbf_bytes);

    const int useWS   = (ws_size >= 256 + bits_bytes) ? 1 : 0;
    const int usePrep = (ws_size >= 256 + bits_bytes + 2 * kbf_bytes) ? 1 : 0;

    mask_probe_kernel<<<1, 64, 0, stream>>>((const unsigned int*)mask, flag);
    if (usePrep) {
        kv_prep_split<<<(KFRAG_T + VFRAG_T) / 256, 256, 0, stream>>>(K, V, Kf, Vf);
        attn_fused_split<<<NBLK, NTHR, 0, stream>>>(Q, Kf, Vf, mask, flag,
                                                    bits8, useWS, attn, prob);
    } else {
        attn_fused_reg<<<1024, NTHR, 0, stream>>>(Q, K, V, mask, flag,
                                                  bits16, useWS, attn, prob);
    }
}

// Round 12
// 367.054 us; speedup vs baseline: 1.2029x; 1.2029x over previous
//
#include <hip/hip_runtime.h>
#include <hip/hip_bf16.h>

#define S_LEN 2048
#define D_DIM 64
#define QT    64
#define KT    64
#define NTHR  256
#define NKT   (S_LEN / KT)          // 32
#define NBLK  1024                  // 32 q-tiles * 32 bh
#define PROB_ELEMS 4194304LL        // 2*16*2048*64

typedef float        f32x4  __attribute__((ext_vector_type(4)));
typedef int          i32x4  __attribute__((ext_vector_type(4)));
typedef unsigned int u32x4  __attribute__((ext_vector_type(4)));
typedef short        bf16x8 __attribute__((ext_vector_type(8)));

__device__ __forceinline__ unsigned short f2bf(float f) {
    return __builtin_bit_cast(unsigned short, __float2bfloat16(f));
}
__device__ __forceinline__ int swzc(int row, int ch) {
    return ch ^ ((row ^ (row >> 3)) & 7);
}
__device__ __forceinline__ float4 scale4(float4 v, float s) {
    v.x *= s; v.y *= s; v.z *= s; v.w *= s; return v;
}
__device__ __forceinline__ u32x4 packbf(float4 a, float4 b) {
    u32x4 r;
    r[0] = (unsigned)f2bf(a.x) | ((unsigned)f2bf(a.y) << 16);
    r[1] = (unsigned)f2bf(a.z) | ((unsigned)f2bf(a.w) << 16);
    r[2] = (unsigned)f2bf(b.x) | ((unsigned)f2bf(b.y) << 16);
    r[3] = (unsigned)f2bf(b.z) | ((unsigned)f2bf(b.w) << 16);
    return r;
}
__device__ __forceinline__ unsigned cvtpk(float lo, float hi) {
    unsigned r;
    asm("v_cvt_pk_bf16_f32 %0, %1, %2" : "=v"(r) : "v"(lo), "v"(hi));
    return r;
}
__device__ __forceinline__ void glds16(const unsigned* g, unsigned char* l) {
    __builtin_amdgcn_global_load_lds(
        (const __attribute__((address_space(1))) unsigned*)g,
        (__attribute__((address_space(3))) unsigned*)(void*)l, 16, 0, 0);
}
#define BC8(x) __builtin_bit_cast(bf16x8, (x))
#define MFMA(A, B, C) __builtin_amdgcn_mfma_f32_16x16x32_bf16((A), (B), (C), 0, 0, 0)

// T4 sync: counted vmcnt + raw barrier, no drain. sched_barrier(0) fences
// pin issue order so the count stays valid (rule #18).
#define SFENCE() __builtin_amdgcn_sched_barrier(0)
#define WAITBAR(N)                                                          \
    SFENCE();                                                               \
    asm volatile("s_waitcnt vmcnt(" #N ")" ::: "memory");                   \
    SFENCE();                                                               \
    __builtin_amdgcn_s_barrier();                                           \
    SFENCE();

// -------------------------------------------------------------------------
__global__ void mask_probe_kernel(const unsigned int* __restrict__ m,
                                  int* __restrict__ flag) {
    unsigned int v = m[threadIdx.x];
    unsigned long long ok = __ballot(v <= 1u);
    if (threadIdx.x == 0) *flag = (ok == ~0ULL) ? 1 : 0;
}

// -------------------------------------------------------------------------
// One-shot prep (R8 verbatim): K -> bf16 LDS-image tiles (8KB per (bh,kt),
// swizzled); V -> transposed [d][k] bf16 tile images.
// -------------------------------------------------------------------------
#define KPART 524288   // 32bh * 2048k * 8ch
#define VPART 65536    // 32bh * 32kt * 64d
__global__ __launch_bounds__(256)
void kv_prep(const float* __restrict__ Kg, const float* __restrict__ Vg,
             unsigned* __restrict__ Kbf, unsigned* __restrict__ Vtb) {
    int tid = blockIdx.x * 256 + threadIdx.x;
    if (tid < KPART) {
        int ch = tid & 7, rowg = tid >> 3;
        const float* src = Kg + (long long)rowg * D_DIM + ch * 8;
        float4 a = *(const float4*)src, b = *(const float4*)(src + 4);
        int bh = rowg >> 11, k = rowg & 2047, kt = k >> 6, row = k & 63;
        unsigned* dst = Kbf + ((unsigned)(bh * NKT + kt) << 11)
                            + row * 32 + swzc(row, ch) * 4;
        *(u32x4*)dst = packbf(a, b);
    } else if (tid < KPART + VPART) {
        int idx = tid - KPART;
        int d = idx & 63, kt = (idx >> 6) & 31, bh = idx >> 11;
        const float* vb = Vg + (long long)(bh * S_LEN + kt * KT) * D_DIM + d;
        unsigned* tile = Vtb + ((unsigned)(bh * NKT + kt) << 11) + d * 32;
        #pragma unroll
        for (int ci = 0; ci < 8; ++ci) {
            u32x4 o;
            #pragma unroll
            for (int s = 0; s < 4; ++s) {
                float lo = vb[(ci * 8 + 2 * s) * D_DIM];
                float hi = vb[(ci * 8 + 2 * s + 1) * D_DIM];
                o[s] = (unsigned)f2bf(lo) | ((unsigned)f2bf(hi) << 16);
            }
            *(u32x4*)(tile + swzc(d, ci) * 4) = o;
        }
    }
}

// ---- glds-kernel macros ----
#define GLDS_K(KS, KTV)                                                     \
    { const unsigned* kp_ = Kbf + ktile0 + (unsigned)(KTV) * 2048u;         \
      glds16(kp_ + f0u, (KS) + dst0); glds16(kp_ + f1u, (KS) + dst1); }
#define GLDS_V(VT, KTV)                                                     \
    { const unsigned* vp_ = Vtb + ktile0 + (unsigned)(KTV) * 2048u;         \
      glds16(vp_ + f0u, (VT) + dst0); glds16(vp_ + f1u, (VT) + dst1); }

// mask raw prefetch (4 vmem loads either path) + bits assembly at consume
#define PREF_MASKF(MI4, MU, KTV)                                            \
    { if (mask32) {                                                         \
        _Pragma("unroll")                                                   \
        for (int n_ = 0; n_ < 4; ++n_)                                      \
          MI4[n_] = *(const i32x4*)(maskI + rowoff                          \
                      + (unsigned)((KTV) * KT + n_ * 16 + 4 * g));          \
      } else {                                                              \
        _Pragma("unroll")                                                   \
        for (int n_ = 0; n_ < 4; ++n_)                                      \
          MU[n_] = *(const unsigned*)(maskB + rowoff                        \
                      + (unsigned)((KTV) * KT + n_ * 16 + 4 * g));          \
      } }

#define BITS16F(DST, MI4, MU)                                               \
    { unsigned bz_ = 0u;                                                    \
      if (mask32) {                                                         \
        _Pragma("unroll")                                                   \
        for (int n_ = 0; n_ < 4; ++n_)                                      \
          bz_ |= ((MI4[n_][0] ? 1u : 0u) | (MI4[n_][1] ? 2u : 0u) |         \
                  (MI4[n_][2] ? 4u : 0u) | (MI4[n_][3] ? 8u : 0u)) << (n_ * 4); \
      } else {                                                              \
        _Pragma("unroll")                                                   \
        for (int n_ = 0; n_ < 4; ++n_) { unsigned mb_ = MU[n_];             \
          bz_ |= (((mb_ & 0xffu) ? 1u : 0u) | ((mb_ & 0xff00u) ? 2u : 0u) | \
                  ((mb_ & 0xff0000u) ? 4u : 0u) |                           \
                  ((mb_ & 0xff000000u) ? 8u : 0u)) << (n_ * 4); }           \
      }                                                                     \
      (DST) = bz_; }

#define GLOAD_BITS(DST, KTV)                                                \
    { (DST) = (unsigned)bitsWS[bitbase + (unsigned)(KTV) * NTHR]; }

#define GP1_TILE(KS, BITS)                                                  \
    { unsigned bb = (BITS);                                                 \
      _Pragma("unroll")                                                     \
      for (int n = 0; n < 4; ++n) {                                         \
        int rowk = n * 16 + c;                                              \
        bf16x8 kf0 = *(const bf16x8*)((KS) + rowk * 128 + swzc(rowk, g) * 16);     \
        bf16x8 kf1 = *(const bf16x8*)((KS) + rowk * 128 + swzc(rowk, 4 + g) * 16); \
        f32x4 acc = {0.f, 0.f, 0.f, 0.f};                                   \
        acc = MFMA(kf0, qf0, acc); acc = MFMA(kf1, qf1, acc);               \
        unsigned mb = bb >> (n * 4);                                        \
        psum += (mb & 1u) ? 0.f : __expf(acc[0]);                           \
        psum += (mb & 2u) ? 0.f : __expf(acc[1]);                           \
        psum += (mb & 4u) ? 0.f : __expf(acc[2]);                           \
        psum += (mb & 8u) ? 0.f : __expf(acc[3]);                           \
      } }

#define GP2_TILE(KS, VT, BITS, KTV)                                         \
    { unsigned bb = (BITS);                                                 \
      _Pragma("unroll")                                                     \
      for (int n = 0; n < 4; ++n) {                                         \
        int rowk = n * 16 + c;                                              \
        bf16x8 kf0 = *(const bf16x8*)((KS) + rowk * 128 + swzc(rowk, g) * 16);     \
        bf16x8 kf1 = *(const bf16x8*)((KS) + rowk * 128 + swzc(rowk, 4 + g) * 16); \
        f32x4 acc = {0.f, 0.f, 0.f, 0.f};                                   \
        acc = MFMA(kf0, qf0, acc); acc = MFMA(kf1, qf1, acc);               \
        unsigned mb = bb >> (n * 4);                                        \
        f32x4 ev;                                                           \
        ev[0] = (mb & 1u) ? 0.f : __expf(acc[0]) * rinv;                    \
        ev[1] = (mb & 2u) ? 0.f : __expf(acc[1]) * rinv;                    \
        ev[2] = (mb & 4u) ? 0.f : __expf(acc[2]) * rinv;                    \
        ev[3] = (mb & 8u) ? 0.f : __expf(acc[3]) * rinv;                    \
        unsigned idx0 = rowoff + (unsigned)((KTV) * KT + n * 16 + 4 * g);   \
        *(f32x4*)(attnOut + idx0) = ev;     /* plain store (R10) */         \
        uint2 pkv; pkv.x = cvtpk(ev[0], ev[1]); pkv.y = cvtpk(ev[2], ev[3]);\
        int kloc = n * 16 + 4 * g;                                          \
        *(uint2*)(Ps + ql * 128 + swzc(ql, kloc >> 3) * 16 + (kloc & 7) * 2) = pkv; \
      }                                                                     \
      { bf16x8 pa0 = *(const bf16x8*)(Ps + ql * 128 + swzc(ql, g) * 16);    \
        bf16x8 pa1 = *(const bf16x8*)(Ps + ql * 128 + swzc(ql, 4 + g) * 16);\
        __builtin_amdgcn_s_setprio(1);                                      \
        _Pragma("unroll")                                                   \
        for (int df = 0; df < 4; ++df) {                                    \
            int d = df * 16 + c;                                            \
            bf16x8 vb0 = *(const bf16x8*)((VT) + d * 128 + swzc(d, g) * 16);     \
            bf16x8 vb1 = *(const bf16x8*)((VT) + d * 128 + swzc(d, 4 + g) * 16); \
            pacc[df] = MFMA(pa0, vb0, pacc[df]);                            \
            pacc[df] = MFMA(pa1, vb1, pacc[df]);                            \
        }                                                                   \
        __builtin_amdgcn_s_setprio(0); } }

// -------------------------------------------------------------------------
// Main kernel: R8 structure + counted-vmcnt barriers (T4).
// Per half-tile: stage(next) -> compute(cur) -> vmcnt(N) -> s_barrier.
// Phase 1 N=1 (leave bits store), phase 2 N=4 (leave 4 attn stores).
// -------------------------------------------------------------------------
__global__ __launch_bounds__(NTHR, 4)
void attn_fused_glds(const float* __restrict__ Qg,
                     const unsigned* __restrict__ Kbf,
                     const unsigned* __restrict__ Vtb,
                     const unsigned char* __restrict__ maskB,
                     const int* __restrict__ flagp,
                     unsigned short* __restrict__ bitsWS, int useWS,
                     float* __restrict__ attnOut, float* __restrict__ probOut) {
    __shared__ unsigned char sm[40960];
    unsigned char* Ks0 = sm;
    unsigned char* Ks1 = sm + 8192;
    unsigned char* Vt0 = sm + 16384;
    unsigned char* Vt1 = sm + 24576;
    unsigned char* Ps  = sm + 32768;

    const int t = threadIdx.x;
    const int lane = t & 63, w = t >> 6, c = lane & 15, g = lane >> 4;
    (void)lane;

    const int orig = blockIdx.x;
    const int virt = (orig & 7) * 128 + (orig >> 3);   // XCD swizzle
    const int qt = virt & 31, bh = virt >> 5;
    const int mask32 = *flagp;
    const int* maskI = (const int*)maskB;

    const int qrowbase = bh * S_LEN + qt * QT;
    const int ql = w * 16 + c;
    const unsigned rowoff = (unsigned)(qrowbase + ql) * (unsigned)S_LEN;
    const unsigned bitbase = (unsigned)virt * NKT * NTHR + (unsigned)t;
    const unsigned ktile0 = (unsigned)(bh * NKT) << 11;

    const int f0u = t * 4, f1u = (NTHR + t) * 4;
    const int dst0 = (t & ~63) * 16, dst1 = (NTHR + (t & ~63)) * 16;

    // ---- stage Q (pre-scaled 1/8) into Ps, keep fragments ----
    #pragma unroll
    for (int i = 0; i < 2; ++i) {
        int flat = i * NTHR + t, row = flat >> 3, ch = flat & 7;
        const float* src = Qg + (qrowbase + row) * D_DIM + ch * 8;
        float4 a = *(const float4*)src, b = *(const float4*)(src + 4);
        *(u32x4*)(Ps + row * 128 + swzc(row, ch) * 16) =
            packbf(scale4(a, 0.125f), scale4(b, 0.125f));
    }
    __syncthreads();
    bf16x8 qf0 = *(const bf16x8*)(Ps + ql * 128 + swzc(ql, g) * 16);
    bf16x8 qf1 = *(const bf16x8*)(Ps + ql * 128 + swzc(ql, 4 + g) * 16);

    // =================== PHASE 1: rowsum + mask bits ===================
    float psum = 0.f;
    {
        unsigned bA, bB;
        i32x4 mAi[4], mBi[4];
        unsigned mAu[4], mBu[4];

        GLDS_K(Ks0, 0)
        PREF_MASKF(mAi, mAu, 0)
        WAITBAR(0)                       // one-time full drain

        for (int j = 0; j < NKT / 2; ++j) {
            const int ktA = 2 * j, ktB = 2 * j + 1;
            GLDS_K(Ks1, ktB)
            PREF_MASKF(mBi, mBu, ktB)
            SFENCE();
            BITS16F(bA, mAi, mAu)
            GP1_TILE(Ks0, bA)
            if (useWS) bitsWS[bitbase + (unsigned)ktA * NTHR] = (unsigned short)bA;
            WAITBAR(1)                   // retire L(ktB); leave bits store

            if (j + 1 < NKT / 2) {
                GLDS_K(Ks0, ktA + 2)
                PREF_MASKF(mAi, mAu, ktA + 2)
            }
            SFENCE();
            BITS16F(bB, mBi, mBu)
            GP1_TILE(Ks1, bB)
            if (useWS) bitsWS[bitbase + (unsigned)ktB * NTHR] = (unsigned short)bB;
            WAITBAR(1)
        }
    }
    float s = psum;
    s += __shfl_xor(s, 16, 64);
    s += __shfl_xor(s, 32, 64);
    const float rinv = 1.0f / s;

    // =================== PHASE 2: attn + PV ===================
    f32x4 pacc[4];
    #pragma unroll
    for (int d = 0; d < 4; ++d) pacc[d] = (f32x4){0.f, 0.f, 0.f, 0.f};
    {
        unsigned bA, bB;
        GLDS_K(Ks0, 0) GLDS_V(Vt0, 0)
        GLOAD_BITS(bA, 0)
        WAITBAR(0)                       // one-time full drain

        for (int j = 0; j < NKT / 2; ++j) {
            const int ktA = 2 * j, ktB = 2 * j + 1;
            GLDS_K(Ks1, ktB) GLDS_V(Vt1, ktB)
            GLOAD_BITS(bB, ktB)
            SFENCE();
            GP2_TILE(Ks0, Vt0, bA, ktA)
            WAITBAR(4)                   // retire L(ktB); leave 4 attn stores

            if (j + 1 < NKT / 2) {
                GLDS_K(Ks0, ktA + 2) GLDS_V(Vt0, ktA + 2)
                GLOAD_BITS(bA, ktA + 2)
            }
            SFENCE();
            GP2_TILE(Ks1, Vt1, bB, ktB)
            WAITBAR(4)
        }
    }

    #pragma unroll
    for (int df = 0; df < 4; ++df)
        #pragma unroll
        for (int r = 0; r < 4; ++r) {
            int qe = w * 16 + g * 4 + r;
            probOut[(long long)(qrowbase + qe) * D_DIM + df * 16 + c] = pacc[df][r];
        }
}

// -------------------------------------------------------------------------
// Fallback (R10 register-staging kernel) if ws too small for prep images.
// -------------------------------------------------------------------------
#define FB_MBITS(DST, KTV)                                                  \
    { unsigned bz_ = 0u;                                                    \
      _Pragma("unroll")                                                     \
      for (int n_ = 0; n_ < 4; ++n_) {                                      \
        unsigned idx_ = rowoff + (unsigned)((KTV) * KT + n_ * 16 + 4 * g);  \
        if (mask32) {                                                       \
            i32x4 m4_ = *(const i32x4*)(maskI + idx_);                      \
            bz_ |= ((m4_[0] ? 1u : 0u) | (m4_[1] ? 2u : 0u) |               \
                    (m4_[2] ? 4u : 0u) | (m4_[3] ? 8u : 0u)) << (n_ * 4);   \
        } else {                                                            \
            unsigned mb_ = *(const unsigned*)(maskB + idx_);                \
            bz_ |= (((mb_ & 0xffu) ? 1u : 0u) | ((mb_ & 0xff00u) ? 2u : 0u) | \
                    ((mb_ & 0xff0000u) ? 4u : 0u) |                         \
                    ((mb_ & 0xff000000u) ? 8u : 0u)) << (n_ * 4);           \
        } }                                                                 \
      (DST) = bz_; }

#define FB_BITS2(DST, KTV)                                                  \
    { if (useWS) (DST) = (unsigned)bitsWS[bitbase + (unsigned)(KTV)*NTHR];  \
      else FB_MBITS(DST, KTV) }

#define FB_LOAD_K(KP, KTV)                                                  \
    { _Pragma("unroll")                                                     \
      for (int i = 0; i < 2; ++i) {                                         \
        int flat = i * NTHR + t, row = flat >> 3, ch = flat & 7;            \
        const float* src = Kg + (kbase + (KTV) * KT + row) * D_DIM + ch * 8;\
        float4 a = *(const float4*)src, b = *(const float4*)(src + 4);      \
        KP[i] = packbf(a, b);                                               \
      } }
#define FB_STAGE_K(KS, KP)                                                  \
    { _Pragma("unroll")                                                     \
      for (int i = 0; i < 2; ++i) {                                         \
        int flat = i * NTHR + t, row = flat >> 3, ch = flat & 7;            \
        *(u32x4*)((KS) + row * 128 + swzc(row, ch) * 16) = KP[i];           \
      } }
#define FB_LOAD_V(VP, KTV)                                                  \
    { const float* src = Vg + (kbase + (KTV) * KT + k0v) * D_DIM + dgv * 8; \
      float4 a = *(const float4*)src, b = *(const float4*)(src + 4);        \
      float4 e4 = *(const float4*)(src + D_DIM);                            \
      float4 f4 = *(const float4*)(src + D_DIM + 4);                        \
      VP[0] = (unsigned)f2bf(a.x) | ((unsigned)f2bf(e4.x) << 16);           \
      VP[1] = (unsigned)f2bf(a.y) | ((unsigned)f2bf(e4.y) << 16);           \
      VP[2] = (unsigned)f2bf(a.z) | ((unsigned)f2bf(e4.z) << 16);           \
      VP[3] = (unsigned)f2bf(a.w) | ((unsigned)f2bf(e4.w) << 16);           \
      VP[4] = (unsigned)f2bf(b.x) | ((unsigned)f2bf(f4.x) << 16);           \
      VP[5] = (unsigned)f2bf(b.y) | ((unsigned)f2bf(f4.y) << 16);           \
      VP[6] = (unsigned)f2bf(b.z) | ((unsigned)f2bf(f4.z) << 16);           \
      VP[7] = (unsigned)f2bf(b.w) | ((unsigned)f2bf(f4.w) << 16); }
#define FB_STAGE_V(VT, VP)                                                  \
    { _Pragma("unroll")                                                     \
      for (int jj = 0; jj < 8; ++jj) {                                      \
        int d = dgv * 8 + jj;                                               \
        *(unsigned*)((VT) + d * 128 + swzc(d, k0v >> 3) * 16 + (k0v & 7) * 2) = VP[jj]; \
      } }

__global__ __launch_bounds__(NTHR, 4)
void attn_fused_reg(const float* __restrict__ Qg, const float* __restrict__ Kg,
                    const float* __restrict__ Vg,
                    const unsigned char* __restrict__ maskB,
                    const int* __restrict__ flagp,
                    unsigned short* __restrict__ bitsWS, int useWS,
                    float* __restrict__ attnOut, float* __restrict__ probOut) {
    __shared__ unsigned char sm[40960];
    unsigned char* Ks0 = sm;
    unsigned char* Ks1 = sm + 8192;
    unsigned char* Vt0 = sm + 16384;
    unsigned char* Vt1 = sm + 24576;
    unsigned char* Ps  = sm + 32768;

    const int t = threadIdx.x;
    const int lane = t & 63, w = t >> 6, c = lane & 15, g = lane >> 4;
    (void)lane;

    const int orig = blockIdx.x;
    const int virt = (orig & 7) * 128 + (orig >> 3);
    const int qt = virt & 31, bh = virt >> 5;
    const int mask32 = *flagp;
    const int* maskI = (const int*)maskB;

    const int qrowbase = bh * S_LEN + qt * QT;
    const int kbase = bh * S_LEN;
    const int ql = w * 16 + c;
    const unsigned rowoff = (unsigned)(qrowbase + ql) * (unsigned)S_LEN;
    const unsigned bitbase = (unsigned)virt * NKT * NTHR + (unsigned)t;
    const int dgv = t & 7, k0v = (t >> 3) * 2;

    #pragma unroll
    for (int i = 0; i < 2; ++i) {
        int flat = i * NTHR + t, row = flat >> 3, ch = flat & 7;
        const float* src = Qg + (qrowbase + row) * D_DIM + ch * 8;
        float4 a = *(const float4*)src, b = *(const float4*)(src + 4);
        *(u32x4*)(Ps + row * 128 + swzc(row, ch) * 16) =
            packbf(scale4(a, 0.125f), scale4(b, 0.125f));
    }
    __syncthreads();
    bf16x8 qf0 = *(const bf16x8*)(Ps + ql * 128 + swzc(ql, g) * 16);
    bf16x8 qf1 = *(const bf16x8*)(Ps + ql * 128 + swzc(ql, 4 + g) * 16);
    __syncthreads();

    float psum = 0.f;
    u32x4 kpA[2], kpB[2];
    unsigned bA, bB;
    FB_LOAD_K(kpA, 0)
    FB_MBITS(bA, 0)

    for (int j = 0; j < NKT / 2; ++j) {
        const int ktA = 2 * j, ktB = 2 * j + 1;
        FB_STAGE_K(Ks0, kpA)
        FB_LOAD_K(kpB, ktB)
        FB_MBITS(bB, ktB)
        __syncthreads();
        GP1_TILE(Ks0, bA)
        if (useWS) bitsWS[bitbase + (unsigned)ktA * NTHR] = (unsigned short)bA;
        FB_STAGE_K(Ks1, kpB)
        if (j + 1 < NKT / 2) {
            FB_LOAD_K(kpA, ktA + 2)
            FB_MBITS(bA, ktA + 2)
        }
        __syncthreads();
        GP1_TILE(Ks1, bB)
        if (useWS) bitsWS[bitbase + (unsigned)ktB * NTHR] = (unsigned short)bB;
    }

    float s = psum;
    s += __shfl_xor(s, 16, 64);
    s += __shfl_xor(s, 32, 64);
    const float rinv = 1.0f / s;

    f32x4 pacc[4];
    #pragma unroll
    for (int d = 0; d < 4; ++d) pacc[d] = (f32x4){0.f, 0.f, 0.f, 0.f};

    unsigned vpA[8], vpB[8];
    FB_LOAD_K(kpA, 0)
    FB_LOAD_V(vpA, 0)
    FB_BITS2(bA, 0)
    __syncthreads();

    for (int j = 0; j < NKT / 2; ++j) {
        const int ktA = 2 * j, ktB = 2 * j + 1;
        FB_STAGE_K(Ks0, kpA)
        FB_STAGE_V(Vt0, vpA)
        FB_LOAD_K(kpB, ktB)
        FB_LOAD_V(vpB, ktB)
        FB_BITS2(bB, ktB)
        __syncthreads();
        GP2_TILE(Ks0, Vt0, bA, ktA)
        FB_STAGE_K(Ks1, kpB)
        FB_STAGE_V(Vt1, vpB)
        if (j + 1 < NKT / 2) {
            FB_LOAD_K(kpA, ktA + 2)
            FB_LOAD_V(vpA, ktA + 2)
            FB_BITS2(bA, ktA + 2)
        }
        __syncthreads();
        GP2_TILE(Ks1, Vt1, bB, ktB)
    }

    #pragma unroll
    for (int df = 0; df < 4; ++df)
        #pragma unroll
        for (int r = 0; r < 4; ++r) {
            int qe = w * 16 + g * 4 + r;
            probOut[(long long)(qrowbase + qe) * D_DIM + df * 16 + c] = pacc[df][r];
        }
}

// -------------------------------------------------------------------------
extern "C" void kernel_launch(void* const* d_in, const int* in_sizes, int n_in,
                              void* d_out, int out_size, void* d_ws, size_t ws_size,
                              hipStream_t stream) {
    const float* Q = (const float*)d_in[0];
    const float* K = (const float*)d_in[1];
    const float* V = (const float*)d_in[2];
    const unsigned char* mask = (const unsigned char*)d_in[3];

    float* prob = (float*)d_out;
    float* attn = (float*)d_out + PROB_ELEMS;

    const size_t bits_bytes = (size_t)NBLK * NKT * NTHR * 2ull;   // 16.78 MB
    const size_t kbf_bytes  = 8388608ull;                          // per tensor
    int* flag = (int*)d_ws;
    unsigned short* bitsWS = (unsigned short*)((char*)d_ws + 256);
    unsigned* Kbf = (unsigned*)((char*)d_ws + 256 + bits_bytes);
    unsigned* Vtb = (unsigned*)((char*)d_ws + 256 + bits_bytes + kbf_bytes);

    const int useWS   = (ws_size >= 256 + bits_bytes) ? 1 : 0;
    const int usePrep = (ws_size >= 256 + bits_bytes + 2 * kbf_bytes) ? 1 : 0;

    mask_probe_kernel<<<1, 64, 0, stream>>>((const unsigned int*)mask, flag);
    if (usePrep && useWS) {
        kv_prep<<<(KPART + VPART) / 256, 256, 0, stream>>>(K, V, Kbf, Vtb);
        attn_fused_glds<<<NBLK, NTHR, 0, stream>>>(Q, Kbf, Vtb, mask, flag,
                                                   bitsWS, useWS, attn, prob);
    } else {
        attn_fused_reg<<<NBLK, NTHR, 0, stream>>>(Q, K, V, mask, flag,
                                                  bitsWS, useWS, attn, prob);
    }
}